// Round 5
// baseline (301.039 us; speedup 1.0000x reference)
//
#include <hip/hip_runtime.h>

// LSTM cell, fused: B=1024, U=2048.
// Kernel 0: xhb (bf16 [1024][4096]) = concat(x,h) converted once  -> d_ws (8 MB)
// Kernel 1: ifgo = xhb @ w (fp32 w converted in-flight), gates fused in epilogue,
//           d_out = [h_new, h_new, c_new].
// R5 vs R4 (153us kernel, L2-bytes+issue-bound):
//  - A staged from pre-converted bf16 (half L2 bytes, no cvt, coalesced 16B)
//  - B loads dwordx4 (8 insts/thread vs 32 scalar), swizzle key (row^(row>>2))&7
//  - s_setprio(1) around MFMA cluster

#define BDIM   1024
#define UDIM   2048
#define KDIM   4096
#define NDIM   8192
#define BM 128
#define BK 64
#define NT (KDIM / BK)

typedef __attribute__((ext_vector_type(4))) float        f32x4;
typedef __attribute__((ext_vector_type(8))) short        short8;
typedef __attribute__((ext_vector_type(4))) unsigned int u32x4;

__device__ inline unsigned int cvt_pk_bf16(float lo, float hi) {
    unsigned int r;
    asm("v_cvt_pk_bf16_f32 %0, %1, %2" : "=v"(r) : "v"(lo), "v"(hi));
    return r;
}
__device__ inline float fast_sigmoid(float v) {
    return __builtin_amdgcn_rcpf(1.f + __expf(-v));
}
__device__ inline float fast_tanh(float v) {
    float t = __expf(-2.f * __builtin_fabsf(v));
    float r = (1.f - t) * __builtin_amdgcn_rcpf(1.f + t);
    return __builtin_copysignf(r, v);
}

// ---------------------------------------------------------------------------
// xhb[r][0..2047] = bf16(x[r]),  xhb[r][2048..4095] = bf16(h[r])
// ---------------------------------------------------------------------------
__global__ __launch_bounds__(256)
void concat_bf16(const float* __restrict__ x, const float* __restrict__ h,
                 unsigned short* __restrict__ xhb) {
    int idx = blockIdx.x * 256 + threadIdx.x;     // 0 .. 524287 (8 elems each)
    int r = idx >> 9;                             // row (512 groups of 8 / row)
    int g = idx & 511;
    const float* src = (g < 256) ? x + (size_t)r * UDIM + g * 8
                                 : h + (size_t)r * UDIM + (g - 256) * 8;
    f32x4 a = *(const f32x4*)src;
    f32x4 b = *(const f32x4*)(src + 4);
    u32x4 u;
    u[0] = cvt_pk_bf16(a[0], a[1]);
    u[1] = cvt_pk_bf16(a[2], a[3]);
    u[2] = cvt_pk_bf16(b[0], b[1]);
    u[3] = cvt_pk_bf16(b[2], b[3]);
    *(u32x4*)(xhb + (size_t)r * KDIM + g * 8) = u;
}

// ---------------------------------------------------------------------------
// Fused GEMM+gates. Block = 128 rows x 32 u-cols (4 gate tiles, n' = gate*32+du).
// 4 waves, each 32 rows x 128 n'. LDS dbuf, XOR swizzle, 2-deep prefetch.
// ---------------------------------------------------------------------------
__global__ __launch_bounds__(256, 2)
void lstm_fused(const unsigned short* __restrict__ xhb, const float* __restrict__ c,
                const float* __restrict__ w, float* __restrict__ out) {
    __shared__ unsigned short As[2][BM * BK];   // 2 x 16 KiB
    __shared__ unsigned short Bs[2][BM * BK];   // 2 x 16 KiB

    const int tid  = threadIdx.x;
    const int lane = tid & 63;
    const int wid  = tid >> 6;
    const int lrow = lane & 15;
    const int lk   = lane >> 4;

    const int m0 = blockIdx.y * BM;
    const int u0 = blockIdx.x * 32;

    // A staging map: inst p -> row = p*32 + wid*8 + (lane>>3), chunk = lane&7
    const int ar_base = wid * 8 + (lane >> 3);
    const int ac      = lane & 7;
    // B staging map: thread -> n-quad nq (np = 4nq..4nq+3), k-group kg (k=8kg..8kg+7)
    const int nq  = tid & 31;
    const int kg  = tid >> 5;
    const int np0 = nq * 4;
    const int bcol = (np0 >> 5) * UDIM + u0 + (np0 & 31);

    f32x4 acc[2][8];
#pragma unroll
    for (int i = 0; i < 2; ++i)
#pragma unroll
        for (int j = 0; j < 8; ++j)
            acc[i][j] = (f32x4){0.f, 0.f, 0.f, 0.f};

    u32x4 avq[4];      // A: 4 x 16B bf16
    f32x4 bvv[8];      // B: 8 x (4 consecutive n) fp32

    auto loadA = [&](int t) {
#pragma unroll
        for (int p = 0; p < 4; ++p) {
            int row = p * 32 + ar_base;
            avq[p] = *(const u32x4*)(xhb + (size_t)(m0 + row) * KDIM + t * BK + ac * 8);
        }
    };
    auto loadB = [&](int t) {
        const float* gp = w + (size_t)(t * BK + kg * 8) * NDIM + bcol;
#pragma unroll
        for (int j = 0; j < 8; ++j)
            bvv[j] = *(const f32x4*)(gp + (size_t)j * NDIM);
    };
    auto writeA = [&](int buf) {
        char* AsB = (char*)As[buf];
#pragma unroll
        for (int p = 0; p < 4; ++p) {
            int row = p * 32 + ar_base;
            *(u32x4*)(AsB + row * 128 + ((ac ^ (row & 7)) << 4)) = avq[p];
        }
    };
    auto writeB = [&](int buf) {
        char* BsB = (char*)Bs[buf];
#pragma unroll
        for (int d = 0; d < 4; ++d) {
            int row = np0 + d;
            u32x4 u;
#pragma unroll
            for (int jj = 0; jj < 4; ++jj)
                u[jj] = cvt_pk_bf16(bvv[2 * jj][d], bvv[2 * jj + 1][d]);
            int ch = kg ^ ((row ^ (row >> 2)) & 7);
            *(u32x4*)(BsB + row * 128 + (ch << 4)) = u;
        }
    };
    auto compute = [&](int buf) {
        const char* AsB = (const char*)As[buf];
        const char* BsB = (const char*)Bs[buf];
#pragma unroll
        for (int kk = 0; kk < 2; ++kk) {
            short8 af[2], bfr[8];
            int cd = kk * 4 + lk;            // desired 16B-chunk index
#pragma unroll
            for (int mi = 0; mi < 2; ++mi) {
                int row = wid * 32 + mi * 16 + lrow;
                af[mi] = *(const short8*)(AsB + row * 128 + ((cd ^ (row & 7)) << 4));
            }
#pragma unroll
            for (int ni = 0; ni < 8; ++ni) {
                int row = ni * 16 + lrow;
                bfr[ni] = *(const short8*)(BsB + row * 128 +
                                           ((cd ^ ((row ^ (row >> 2)) & 7)) << 4));
            }
            __builtin_amdgcn_s_setprio(1);
#pragma unroll
            for (int mi = 0; mi < 2; ++mi)
#pragma unroll
                for (int ni = 0; ni < 8; ++ni)
                    acc[mi][ni] = __builtin_amdgcn_mfma_f32_16x16x32_bf16(
                        af[mi], bfr[ni], acc[mi][ni], 0, 0, 0);
            __builtin_amdgcn_s_setprio(0);
        }
    };

    loadA(0); loadB(0);
    writeA(0); writeB(0);
    loadA(1); loadB(1);
    __syncthreads();

    for (int t = 0; t < NT; ++t) {
        int cur = t & 1;
        if (t + 1 < NT) {
            writeA(cur ^ 1); writeB(cur ^ 1);
            if (t + 2 < NT) { loadA(t + 2); loadB(t + 2); }
        }
        compute(cur);
        __syncthreads();
    }

    // ---- fused gate epilogue ----
    const size_t M = (size_t)BDIM * UDIM;
#pragma unroll
    for (int mi = 0; mi < 2; ++mi) {
        int rbase = m0 + wid * 32 + mi * 16 + lk * 4;
#pragma unroll
        for (int half = 0; half < 2; ++half) {
            int u = u0 + half * 16 + lrow;
            f32x4 iv = acc[mi][0 + half];
            f32x4 fv = acc[mi][2 + half];
            f32x4 gv = acc[mi][4 + half];
            f32x4 ov = acc[mi][6 + half];
#pragma unroll
            for (int r = 0; r < 4; ++r) {
                size_t off = (size_t)(rbase + r) * UDIM + u;
                float cc = fast_sigmoid(fv[r]) * c[off] +
                           fast_sigmoid(iv[r]) * fast_tanh(gv[r]);
                float hh = fast_sigmoid(ov[r]) * fast_tanh(cc);
                out[off]         = hh;
                out[M + off]     = hh;
                out[2 * M + off] = cc;
            }
        }
    }
}

extern "C" void kernel_launch(void* const* d_in, const int* in_sizes, int n_in,
                              void* d_out, int out_size, void* d_ws, size_t ws_size,
                              hipStream_t stream) {
    const float* x = (const float*)d_in[0];
    const float* h = (const float*)d_in[1];
    const float* c = (const float*)d_in[2];
    const float* w = (const float*)d_in[3];
    unsigned short* xhb = (unsigned short*)d_ws;    // 8 MiB bf16
    float* out = (float*)d_out;

    concat_bf16<<<(BDIM * KDIM / 8) / 256, 256, 0, stream>>>(x, h, xhb);

    dim3 grid(UDIM / 32, BDIM / BM);                // (64, 8) = 512 blocks
    lstm_fused<<<grid, 256, 0, stream>>>(xhb, c, w, out);
}